// Round 1
// baseline (1369.114 us; speedup 1.0000x reference)
//
#include <hip/hip_runtime.h>
#include <hip/hip_bf16.h>

// ---------------- problem constants ----------------
#define FIN 165
#define HID 128
#define BM 64          // gemm row tile
#define BN 128         // gemm col tile (== HID)
#define KT 16          // gemm k tile
#define SCHUNK 2048    // scan chunk (256 thr * 8)

// ---------------- CSR build ----------------
__global__ __launch_bounds__(256) void count_deg(const int* __restrict__ dst,
                                                 int* __restrict__ deg, int E, int n) {
    int e = blockIdx.x * 256 + threadIdx.x;
    if (e < E) {
        int d = dst[e];
        if ((unsigned)d < (unsigned)n) atomicAdd(&deg[d], 1);
    }
}

__global__ __launch_bounds__(256) void dinv_k(const int* __restrict__ deg,
                                              float* __restrict__ dinv, int n) {
    int i = blockIdx.x * 256 + threadIdx.x;
    if (i < n) dinv[i] = rsqrtf((float)(deg[i] + 1));   // +1 self loop
}

__global__ __launch_bounds__(256) void scan_partial(const int* __restrict__ deg,
                                                    int* __restrict__ partial, int n) {
    __shared__ int sm[256];
    int base = blockIdx.x * SCHUNK;
    int s = 0;
    for (int i = threadIdx.x; i < SCHUNK; i += 256) {
        int idx = base + i;
        s += (idx < n) ? deg[idx] : 0;
    }
    sm[threadIdx.x] = s;
    __syncthreads();
    for (int off = 128; off > 0; off >>= 1) {
        if (threadIdx.x < off) sm[threadIdx.x] += sm[threadIdx.x + off];
        __syncthreads();
    }
    if (threadIdx.x == 0) partial[blockIdx.x] = sm[0];
}

// single block, 256 threads; nb <= 256 (200000/2048 = 98)
__global__ __launch_bounds__(256) void scan_level2(int* __restrict__ partial, int nb,
                                                   int* __restrict__ rowptr, int n) {
    __shared__ int sm[256];
    int t = threadIdx.x;
    int v = (t < nb) ? partial[t] : 0;
    sm[t] = v;
    __syncthreads();
    for (int off = 1; off < 256; off <<= 1) {
        int u = (t >= off) ? sm[t - off] : 0;
        __syncthreads();
        sm[t] += u;
        __syncthreads();
    }
    if (t < nb) partial[t] = sm[t] - v;      // exclusive
    if (t == 0) rowptr[n] = sm[255];         // total == E
}

__global__ __launch_bounds__(256) void scan_write(const int* __restrict__ deg,
                                                  const int* __restrict__ partial,
                                                  int* __restrict__ rowptr, int n) {
    __shared__ int sm[256];
    int base = blockIdx.x * SCHUNK;
    int vals[8];
    int s = 0;
#pragma unroll
    for (int q = 0; q < 8; ++q) {
        int idx = base + threadIdx.x * 8 + q;
        vals[q] = (idx < n) ? deg[idx] : 0;
        s += vals[q];
    }
    sm[threadIdx.x] = s;
    __syncthreads();
    for (int off = 1; off < 256; off <<= 1) {
        int u = (threadIdx.x >= off) ? sm[threadIdx.x - off] : 0;
        __syncthreads();
        sm[threadIdx.x] += u;
        __syncthreads();
    }
    int excl = partial[blockIdx.x] + (threadIdx.x > 0 ? sm[threadIdx.x - 1] : 0);
#pragma unroll
    for (int q = 0; q < 8; ++q) {
        int idx = base + threadIdx.x * 8 + q;
        if (idx < n) rowptr[idx] = excl;
        excl += vals[q];
    }
}

__global__ __launch_bounds__(256) void fill_csr(const int* __restrict__ src,
                                                const int* __restrict__ dst,
                                                const int* __restrict__ rowptr,
                                                int* __restrict__ fill,
                                                int* __restrict__ col, int E, int n) {
    int e = blockIdx.x * 256 + threadIdx.x;
    if (e < E) {
        int d = dst[e];
        int s = src[e];
        if ((unsigned)d < (unsigned)n && (unsigned)s < (unsigned)n) {
            int pos = atomicAdd(&fill[d], 1);
            col[rowptr[d] + pos] = s;
        }
    }
}

// ---------------- GEMM: H[r,c] = dinv[r] * sum_k X[r,k] W[k,c] ----------------
// X: [n x K] row major, W: [K x 128], H: [n x 128]
__global__ __launch_bounds__(256) void gemm_scale(const float* __restrict__ X,
                                                  const float* __restrict__ W,
                                                  const float* __restrict__ dinv,
                                                  float* __restrict__ H,
                                                  int n, int K) {
    __shared__ float xs[KT][BM];     // transposed x tile
    __shared__ float wsm[KT][BN];
    int r0 = blockIdx.x * BM;
    int tid = threadIdx.x;
    int tr = (tid & 7) * 8;          // 8 rows per thread
    int tc = (tid >> 3) * 4;         // 4 cols per thread
    float acc[8][4] = {};

    for (int kt = 0; kt < K; kt += KT) {
        // load X tile (64 rows x 16 k), transposed into xs[k][r]
        for (int i = tid; i < BM * KT; i += 256) {
            int r = i >> 4;
            int k = i & 15;
            int gr = r0 + r, gk = kt + k;
            float v = 0.f;
            if (gr < n && gk < K) v = X[(long)gr * K + gk];
            xs[k][r] = v;
        }
        // load W tile (16 k x 128 c)
        for (int i = tid; i < KT * BN; i += 256) {
            int k = i >> 7;
            int c = i & 127;
            int gk = kt + k;
            wsm[k][c] = (gk < K) ? W[gk * BN + c] : 0.f;
        }
        __syncthreads();
#pragma unroll
        for (int k = 0; k < KT; ++k) {
            float xv[8];
#pragma unroll
            for (int r = 0; r < 8; ++r) xv[r] = xs[k][tr + r];
            float wv[4];
#pragma unroll
            for (int c = 0; c < 4; ++c) wv[c] = wsm[k][tc + c];
#pragma unroll
            for (int r = 0; r < 8; ++r)
#pragma unroll
                for (int c = 0; c < 4; ++c)
                    acc[r][c] += xv[r] * wv[c];
        }
        __syncthreads();
    }
#pragma unroll
    for (int r = 0; r < 8; ++r) {
        int gr = r0 + tr + r;
        if (gr >= n) continue;
        float s = dinv[gr];
        float4 o;
        o.x = acc[r][0] * s; o.y = acc[r][1] * s;
        o.z = acc[r][2] * s; o.w = acc[r][3] * s;
        *(float4*)&H[(long)gr * BN + tc] = o;
    }
}

// ---------------- aggregation: Y[i] = relu(dinv[i]*(HS[i] + sum_nbr HS[s]) + b) ----------------
__global__ __launch_bounds__(128) void agg_relu(const float* __restrict__ HS,
                                                const int* __restrict__ rowptr,
                                                const int* __restrict__ col,
                                                const float* __restrict__ dinv,
                                                const float* __restrict__ bias,
                                                float* __restrict__ Y, int n) {
    __shared__ int cols[128];
    int i = blockIdx.x;
    int f = threadIdx.x;
    int start = rowptr[i], end = rowptr[i + 1];
    float acc = HS[(long)i * HID + f];      // self loop term (hs[i])
    for (int j0 = start; j0 < end; j0 += 128) {
        int j = j0 + f;
        cols[f] = (j < end) ? col[j] : 0;
        __syncthreads();
        int cnt = min(128, end - j0);
        for (int t = 0; t < cnt; ++t) {
            acc += HS[(long)cols[t] * HID + f];
        }
        __syncthreads();
    }
    float v = acc * dinv[i] + bias[f];
    Y[(long)i * HID + f] = fmaxf(v, 0.f);
}

// ---------------- head: out[i,:2] = Y[i,:] @ Wl + bl ----------------
__global__ __launch_bounds__(256) void head_k(const float* __restrict__ Y,
                                              const float* __restrict__ Wl,
                                              const float* __restrict__ bl,
                                              float* __restrict__ out, int n) {
    int node = blockIdx.x * 4 + (threadIdx.x >> 6);
    int lane = threadIdx.x & 63;
    if (node >= n) return;
    const float* y = Y + (long)node * HID;
    float y0 = y[lane], y1 = y[lane + 64];
    float a = y0 * Wl[lane * 2 + 0] + y1 * Wl[(lane + 64) * 2 + 0];
    float b = y0 * Wl[lane * 2 + 1] + y1 * Wl[(lane + 64) * 2 + 1];
#pragma unroll
    for (int off = 32; off > 0; off >>= 1) {
        a += __shfl_down(a, off);
        b += __shfl_down(b, off);
    }
    if (lane == 0) {
        out[node * 2 + 0] = a + bl[0];
        out[node * 2 + 1] = b + bl[1];
    }
}

// ---------------- launch ----------------
extern "C" void kernel_launch(void* const* d_in, const int* in_sizes, int n_in,
                              void* d_out, int out_size, void* d_ws, size_t ws_size,
                              hipStream_t stream) {
    const float* x  = (const float*)d_in[0];
    const int*   ei = (const int*)d_in[1];
    const float* W1 = (const float*)d_in[2];
    const float* b1 = (const float*)d_in[3];
    const float* W2 = (const float*)d_in[4];
    const float* b2 = (const float*)d_in[5];
    const float* Wl = (const float*)d_in[6];
    const float* bl = (const float*)d_in[7];
    float* out = (float*)d_out;

    int n = in_sizes[0] / FIN;          // 200000
    int E = in_sizes[1] / 2;            // 3200000
    const int* srcp = ei;
    const int* dstp = ei + E;

    char* w = (char*)d_ws;
    auto alloc = [&](size_t bytes) {
        char* p = w;
        w += (bytes + 255) & ~(size_t)255;
        return (void*)p;
    };
    int*   deg     = (int*)  alloc((size_t)n * 4);
    int*   fill    = (int*)  alloc((size_t)n * 4);
    int*   rowptr  = (int*)  alloc(((size_t)n + 1) * 4);
    int    nb      = (n + SCHUNK - 1) / SCHUNK;
    int*   partial = (int*)  alloc((size_t)nb * 4);
    float* dinv    = (float*)alloc((size_t)n * 4);
    int*   colv    = (int*)  alloc((size_t)E * 4);
    float* hbuf    = (float*)alloc((size_t)n * HID * 4);
    float* ybuf    = (float*)alloc((size_t)n * HID * 4);

    hipMemsetAsync(deg, 0, (size_t)n * 4, stream);
    hipMemsetAsync(fill, 0, (size_t)n * 4, stream);

    count_deg<<<(E + 255) / 256, 256, 0, stream>>>(dstp, deg, E, n);
    dinv_k<<<(n + 255) / 256, 256, 0, stream>>>(deg, dinv, n);
    scan_partial<<<nb, 256, 0, stream>>>(deg, partial, n);
    scan_level2<<<1, 256, 0, stream>>>(partial, nb, rowptr, n);
    scan_write<<<nb, 256, 0, stream>>>(deg, partial, rowptr, n);
    fill_csr<<<(E + 255) / 256, 256, 0, stream>>>(srcp, dstp, rowptr, fill, colv, E, n);

    // layer 1: hs1 = (x@W1)*dinv ; y1 = relu(dinv*(hs1 + gather) + b1)
    gemm_scale<<<(n + BM - 1) / BM, 256, 0, stream>>>(x, W1, dinv, hbuf, n, FIN);
    agg_relu<<<n, 128, 0, stream>>>(hbuf, rowptr, colv, dinv, b1, ybuf, n);

    // layer 2
    gemm_scale<<<(n + BM - 1) / BM, 256, 0, stream>>>(ybuf, W2, dinv, hbuf, n, HID);
    agg_relu<<<n, 128, 0, stream>>>(hbuf, rowptr, colv, dinv, b2, ybuf, n);

    // head
    head_k<<<(n + 3) / 4, 256, 0, stream>>>(ybuf, Wl, bl, out, n);
}